// Round 14
// baseline (129.643 us; speedup 1.0000x reference)
//
#include <hip/hip_runtime.h>

// Causal MHA fwd: B=2, N=2048, H=16, D=64. fp32 in / fp32 out.
// Tensors flat row-major (B*H, N, 64). Flash attention, 32x32 MFMA.
//
// Round 25 = Round 24 RESUBMITTED (previous bench was an infra failure:
// "MI355X container failed twice" - no kernel data). Design rationale:
//  - R17 (verified 48us, absmax 0.0234) parameterized to [it0,it1) +
//    SPLIT-K across blocks for the heavy half of the causal triangle.
//  - R19/R20/R23 all failed by changing intra-wave staging mechanics; this
//    changes NONE of the loop body - R17 verbatim, loop bounds only.
//  - Makespan analysis (R22 counters): heavy Tq=15 block = 32 serial
//    barrier-intervals, running ~solo (Occupancy 12%). Split each heavy
//    tile (Tq>=8) k-range in half: lower block = intervals [0,Tq+1)
//    (never reaches diagonal: it<=Tq<2Tq<=itl, diag never fires - the R17
//    body handles it with zero changes), upper block = [Tq+1,2Tq+2)
//    (diagonal as usual). exp2-direct softmax => halves are exact linear
//    partials (l=lA+lB, o=oA+oB; concept correctness-verified in R18).
//  - Partials to workspace (sole-writer regions, no atomics, no memset);
//    combine kernel (256 blocks) sums + divides. Max block length 32->16
//    intervals; grid 768 = 3 concurrent blocks/CU.
//  - Host falls back to the R17-equivalent single launch (mode 0) if
//    ws_size < 17MB - a verified-passing path.
// ws layout: 512 slots x 8320 f32: slot s=bh*8+(Tq-8) (lower), 256+s
// (upper); per slot: l[128] then o[128][64].

typedef short  short8v __attribute__((ext_vector_type(8)));
typedef float  float4v __attribute__((ext_vector_type(4)));
typedef float  float8v __attribute__((ext_vector_type(8)));
typedef float  f32x16  __attribute__((ext_vector_type(16)));

#define NQ 2048
#define DD 64
#define KT 64          // keys per iteration
#define KP 72          // K LDS row pitch (bf16 elts), 144B
#define VP 72          // V^T LDS row pitch
#define SLOT 8320      // ws floats per partial: 128 l + 128*64 o

#define Z16 ((f32x16){0.f,0.f,0.f,0.f,0.f,0.f,0.f,0.f,0.f,0.f,0.f,0.f,0.f,0.f,0.f,0.f})
#define mfma32 __builtin_amdgcn_mfma_f32_32x32x16_bf16

union U4 { unsigned int u[4]; short8v s; };

// truncating pack: two f32 -> two bf16 (lo -> low half) — K/V staging
static __device__ __forceinline__ unsigned int pktr(float lo, float hi) {
    return __builtin_amdgcn_perm(__builtin_bit_cast(unsigned int, hi),
                                 __builtin_bit_cast(unsigned int, lo),
                                 0x07060302);
}
// round-half-up pack — used for Q (once per wave)
static __device__ __forceinline__ unsigned int pkrn(float lo, float hi) {
    unsigned int a = __builtin_bit_cast(unsigned int, hi) + 0x8000u;
    unsigned int b = __builtin_bit_cast(unsigned int, lo) + 0x8000u;
    return __builtin_amdgcn_perm(a, b, 0x07060302);
}
// RNE pack via HW instruction (P values)
static __device__ __forceinline__ unsigned int cvtpk(float lo, float hi) {
    unsigned int d;
    asm("v_cvt_pk_bf16_f32 %0, %1, %2" : "=v"(d) : "v"(lo), "v"(hi));
    return d;
}
// raw HW exp2 (no OCML guard); exp2(-3e38) = 0 handles the causal mask
static __device__ __forceinline__ float fexp2(float x) {
    float y;
    asm("v_exp_f32 %0, %1" : "=v"(y) : "v"(x));
    return y;
}

// Build one PA fragment (A-operand slice: P[q][16s'+8h+j], j=0..7)
// from sT regs B..B+7. After swap: P0,P1,P2,P3 = words w0..w3. (verified R16)
#define MK_PA(dst, S, B)                                                     \
    {                                                                        \
        unsigned int P0 = cvtpk(S[(B) + 0], S[(B) + 1]);                     \
        unsigned int P1 = cvtpk(S[(B) + 2], S[(B) + 3]);                     \
        unsigned int P2 = cvtpk(S[(B) + 4], S[(B) + 5]);                     \
        unsigned int P3 = cvtpk(S[(B) + 6], S[(B) + 7]);                     \
        asm("v_permlane32_swap_b32 %0, %1" : "+v"(P0), "+v"(P2));            \
        asm("v_permlane32_swap_b32 %0, %1" : "+v"(P1), "+v"(P3));            \
        U4 w_;                                                               \
        w_.u[0] = P0; w_.u[1] = P1; w_.u[2] = P2; w_.u[3] = P3;              \
        dst = w_.s;                                                          \
    }

#define VF(td, s) (*(const short8v*)&Vt[cur][((td) * 32 + q31) * VP + (s) * 16 + h * 8])

__global__ __launch_bounds__(256, 2) void mha_fwd_kernel(
    const float* __restrict__ Kg,
    const float* __restrict__ Qg,
    const float* __restrict__ Vg,
    float* __restrict__ Og,
    float* __restrict__ ws,
    const int mode)
{
    __shared__ __align__(16) unsigned short Klds[2][KT * KP];  // 2 x 9216 B
    __shared__ __align__(16) unsigned short Vt[2][DD * VP];    // 2 x 9216 B

    const int t    = threadIdx.x;
    const int lane = t & 63;
    const int wave = t >> 6;       // 0..3
    const int q31  = lane & 31;
    const int h    = lane >> 5;

    // ---- block decode ----
    int bh, Tq, it0, it1;
    bool partial;
    float* wp = nullptr;
    const int b = blockIdx.x;
    if (mode == 0) {
        // R17 map: 512 blocks, heavy(15-jj)/light(jj) pairs, full range
        const int rb = b & 255;
        bh = rb & 31;
        const int jj = rb >> 5;
        Tq = (b >> 8) ? jj : (15 - jj);
        it0 = 0; it1 = 2 * Tq + 2;
        partial = false;
    } else {
        // split map: 768 blocks
        const int reg = b >> 8;        // 0=upper half, 1=lower half, 2=light
        const int rb  = b & 255;
        bh = rb & 31;
        const int jj = rb >> 5;        // 0..7
        if (reg == 2) {
            Tq = 7 - jj;               // light single, full range
            it0 = 0; it1 = 2 * Tq + 2;
            partial = false;
        } else {
            Tq = 15 - jj;              // heavy, split at Tq+1
            const int slot = bh * 8 + (Tq - 8);
            if (reg == 0) { it0 = Tq + 1; it1 = 2 * Tq + 2;           // upper
                            wp = ws + (size_t)(256 + slot) * SLOT; }
            else          { it0 = 0;      it1 = Tq + 1;               // lower
                            wp = ws + (size_t)slot * SLOT; }
            partial = true;
        }
    }

    const int q0  = Tq * 128 + wave * 32;      // wave's 32 q rows
    const int itl = 2 * Tq + (wave >> 1);      // wave's diagonal iteration

    const size_t base = (size_t)bh * NQ * DD;
    const float* Qp = Qg + base;
    const float* Kp = Kg + base;
    const float* Vp = Vg + base;
    float*       Op = Og + base;

    const float sscale = 0.125f * 1.4426950408889634f;  // 1/sqrt(64)*log2(e)

    // staging roles (256 threads) — fully coalesced (verbatim R17):
    const int kr = t >> 3, kc = (t & 7) * 8;   // K: rows kr, kr+32
    const int vd = t & 63, vg = (t >> 6) * 16; // V^T: row vd, keys vg..vg+15

    // ---- Q fragments (B-operand): lane holds Q[q0+q31][s*16+h*8+0..7] ----
    short8v qf[4];
#pragma unroll
    for (int s = 0; s < 4; ++s) {
        float8v a = *(const float8v*)(Qp + (size_t)(q0 + q31) * DD + s * 16 + h * 8);
        U4 w;
#pragma unroll
        for (int i = 0; i < 4; ++i)
            w.u[i] = pkrn(a[2 * i] * sscale, a[2 * i + 1] * sscale);
        qf[s] = w.s;
    }

    float  l_i = 0.0f;
    f32x16 o0 = Z16, o1 = Z16;

    // ---- prologue: stage tile it0 into buffer (it0&1) ----
    {
        const int kb0 = it0 * KT;
        const int pb  = it0 & 1;
        float8v pka0 = *(const float8v*)(Kp + (size_t)(kb0 + kr) * DD + kc);
        float8v pka1 = *(const float8v*)(Kp + (size_t)(kb0 + kr + 32) * DD + kc);
        float pvr[16];
#pragma unroll
        for (int i = 0; i < 16; ++i)
            pvr[i] = Vp[(size_t)(kb0 + vg + i) * DD + vd];
        U4 w0, w1, wv0, wv1;
#pragma unroll
        for (int i = 0; i < 4; ++i) {
            w0.u[i]  = pktr(pka0[2 * i], pka0[2 * i + 1]);
            w1.u[i]  = pktr(pka1[2 * i], pka1[2 * i + 1]);
            wv0.u[i] = pktr(pvr[2 * i], pvr[2 * i + 1]);
            wv1.u[i] = pktr(pvr[8 + 2 * i], pvr[9 + 2 * i]);
        }
        *(short8v*)&Klds[pb][kr * KP + kc]        = w0.s;
        *(short8v*)&Klds[pb][(kr + 32) * KP + kc] = w1.s;
        *(short8v*)&Vt[pb][vd * VP + vg]          = wv0.s;
        *(short8v*)&Vt[pb][vd * VP + vg + 8]      = wv1.s;
    }
    __syncthreads();

    for (int it = it0; it < it1; ++it) {
        const int  cur = it & 1;
        const bool stg = (it + 1 < it1);

        // ---- issue next-tile global loads (R17 mechanics, unchanged) ----
        float8v ka0, ka1;
        float   vr[16];
        if (stg) {
            const int nkb = (it + 1) * KT;
            ka0 = *(const float8v*)(Kp + (size_t)(nkb + kr) * DD + kc);
            ka1 = *(const float8v*)(Kp + (size_t)(nkb + kr + 32) * DD + kc);
#pragma unroll
            for (int i = 0; i < 16; ++i)
                vr[i] = Vp[(size_t)(nkb + vg + i) * DD + vd];
        }

        // ---- compute (wave drops out past its diagonal) — R17 verbatim ----
        if (it <= itl) {
            __builtin_amdgcn_s_setprio(1);
            const bool diag = (it == itl);
            const bool do1  = (!diag) || (wave & 1);  // tile1 live?

            short8v pa0, pa1, pa2, pa3;

            // tile 0: keys it*64 + 0..31
            {
                f32x16 sT = Z16;
#pragma unroll
                for (int s = 0; s < 4; ++s) {
                    short8v kf = *(const short8v*)&Klds[cur][q31 * KP + s * 16 + h * 8];
                    sT = mfma32(kf, qf[s], sT, 0, 0, 0);
                }
                if (diag && !(wave & 1)) {
#pragma unroll
                    for (int r = 0; r < 16; ++r) {
                        const int kcst = (r & 3) + 8 * (r >> 2);
                        if (kcst + 4 * h > q31) sT[r] = -3.0e38f;
                    }
                }
#pragma unroll
                for (int r = 0; r < 16; ++r) sT[r] = fexp2(sT[r]);
                l_i += (((sT[0] + sT[1]) + (sT[2] + sT[3])) +
                        ((sT[4] + sT[5]) + (sT[6] + sT[7]))) +
                       (((sT[8] + sT[9]) + (sT[10] + sT[11])) +
                        ((sT[12] + sT[13]) + (sT[14] + sT[15])));
                MK_PA(pa0, sT, 0);
                MK_PA(pa1, sT, 8);
            }
            o0 = mfma32(pa0, VF(0, 0), o0, 0, 0, 0);
            o1 = mfma32(pa0, VF(1, 0), o1, 0, 0, 0);
            o0 = mfma32(pa1, VF(0, 1), o0, 0, 0, 0);
            o1 = mfma32(pa1, VF(1, 1), o1, 0, 0, 0);

            // tile 1: keys it*64 + 32..63 (skipped when fully masked)
            if (do1) {
                f32x16 sU = Z16;
#pragma unroll
                for (int s = 0; s < 4; ++s) {
                    short8v kf = *(const short8v*)&Klds[cur][(32 + q31) * KP + s * 16 + h * 8];
                    sU = mfma32(kf, qf[s], sU, 0, 0, 0);
                }
                if (diag && (wave & 1)) {
#pragma unroll
                    for (int r = 0; r < 16; ++r) {
                        const int kcst = (r & 3) + 8 * (r >> 2);
                        if (kcst + 4 * h > q31) sU[r] = -3.0e38f;
                    }
                }
#pragma unroll
                for (int r = 0; r < 16; ++r) sU[r] = fexp2(sU[r]);
                l_i += (((sU[0] + sU[1]) + (sU[2] + sU[3])) +
                        ((sU[4] + sU[5]) + (sU[6] + sU[7]))) +
                       (((sU[8] + sU[9]) + (sU[10] + sU[11])) +
                        ((sU[12] + sU[13]) + (sU[14] + sU[15])));
                MK_PA(pa2, sU, 0);
                MK_PA(pa3, sU, 8);
                o0 = mfma32(pa2, VF(0, 2), o0, 0, 0, 0);
                o1 = mfma32(pa2, VF(1, 2), o1, 0, 0, 0);
                o0 = mfma32(pa3, VF(0, 3), o0, 0, 0, 0);
                o1 = mfma32(pa3, VF(1, 3), o1, 0, 0, 0);
            }
            __builtin_amdgcn_s_setprio(0);
        }

        // ---- write staged regs -> buf[cur^1] (R17 verbatim) ----
        if (stg) {
            U4 w0, w1, wv0, wv1;
#pragma unroll
            for (int i = 0; i < 4; ++i) {
                w0.u[i]  = pktr(ka0[2 * i], ka0[2 * i + 1]);
                w1.u[i]  = pktr(ka1[2 * i], ka1[2 * i + 1]);
                wv0.u[i] = pktr(vr[2 * i], vr[2 * i + 1]);
                wv1.u[i] = pktr(vr[8 + 2 * i], vr[9 + 2 * i]);
            }
            *(short8v*)&Klds[cur ^ 1][kr * KP + kc]        = w0.s;
            *(short8v*)&Klds[cur ^ 1][(kr + 32) * KP + kc] = w1.s;
            *(short8v*)&Vt[cur ^ 1][vd * VP + vg]          = wv0.s;
            *(short8v*)&Vt[cur ^ 1][vd * VP + vg + 8]      = wv1.s;
        }

        __syncthreads();  // buf[cur^1] ready; buf[cur] reads drained
    }

    // ---- epilogue ----
    const float rs = l_i + __shfl_xor(l_i, 32);   // l for q-row q31 (both h)
    if (partial) {
        // write raw partials: l then o (no divide); sole writer per region
        float* wl = wp;
        float* wo = wp + 128;
        if (h == 0) wl[wave * 32 + q31] = rs;
#pragma unroll
        for (int r = 0; r < 16; ++r) {
            const int qrow = (r & 3) + 8 * (r >> 2) + 4 * h;
            wo[(size_t)(wave * 32 + qrow) * DD + q31]      = o0[r];
            wo[(size_t)(wave * 32 + qrow) * DD + 32 + q31] = o1[r];
        }
    } else {
        const float rinv = 1.0f / rs;
#pragma unroll
        for (int r = 0; r < 16; ++r) {
            const int   qrow = (r & 3) + 8 * (r >> 2) + 4 * h;
            const float lv   = __shfl(rinv, qrow, 64);
            Op[(size_t)(q0 + qrow) * DD + q31]      = o0[r] * lv;
            Op[(size_t)(q0 + qrow) * DD + 32 + q31] = o1[r] * lv;
        }
    }
}

// combine: out[q][d] = (oA + oB) / (lA + lB) for the 256 split tiles
__global__ __launch_bounds__(256, 8) void mha_combine_kernel(
    const float* __restrict__ ws,
    float* __restrict__ Og)
{
    const int s  = blockIdx.x;         // slot 0..255
    const int bh = s >> 3;
    const int Tq = 8 + (s & 7);
    const float* A = ws + (size_t)s * SLOT;
    const float* B = ws + (size_t)(256 + s) * SLOT;

    const int t   = threadIdx.x;
    const int row = t >> 1;            // 0..127
    const int ch  = (t & 1) * 32;      // col half

    const float inv = 1.0f / (A[row] + B[row]);
    const float* a = A + 128 + (size_t)row * DD + ch;
    const float* b = B + 128 + (size_t)row * DD + ch;
    float* op = Og + ((size_t)bh * NQ + Tq * 128 + row) * DD + ch;
#pragma unroll
    for (int i = 0; i < 8; ++i) {
        float4v va = *(const float4v*)(a + i * 4);
        float4v vb = *(const float4v*)(b + i * 4);
        float4v vo;
#pragma unroll
        for (int j = 0; j < 4; ++j) vo[j] = (va[j] + vb[j]) * inv;
        *(float4v*)(op + i * 4) = vo;
    }
}

extern "C" void kernel_launch(void* const* d_in, const int* in_sizes, int n_in,
                              void* d_out, int out_size, void* d_ws, size_t ws_size,
                              hipStream_t stream) {
    const float* keys    = (const float*)d_in[0];
    const float* queries = (const float*)d_in[1];
    const float* values  = (const float*)d_in[2];
    float* out           = (float*)d_out;
    float* ws            = (float*)d_ws;

    const size_t need = (size_t)512 * SLOT * sizeof(float);  // ~17 MB
    if (ws != nullptr && ws_size >= need) {
        // split path: 768 blocks (256 upper halves, 256 lower, 256 light)
        mha_fwd_kernel<<<dim3(768), dim3(256), 0, stream>>>(
            keys, queries, values, out, ws, 1);
        mha_combine_kernel<<<dim3(256), dim3(256), 0, stream>>>(ws, out);
    } else {
        // fallback: verified R17 single-kernel path
        mha_fwd_kernel<<<dim3(512), dim3(256), 0, stream>>>(
            keys, queries, values, out, ws, 0);
    }
}